// Round 14
// baseline (198.044 us; speedup 1.0000x reference)
//
#include <hip/hip_runtime.h>
#include <math.h>

// ---------------------------------------------------------------------------
// Problem: B=4, L=4096, D=P=256, tau=0.5
// out = (1/8) * sum_{b,l} [ log(S1-e^2) + log(S2-e^2) - 4*d[b,l] ]
//   S[b,q] = sum_{m<2L} exp(2 * Zhat[b,q].Zhat[b,m]),  Zhat = [z1n; z2n]
// R25 = R24 + fusedproj de-staged.  R24 postmortem: proj's 16 steps have
// only ~310cyc MFMA each vs gram's ~1100 -> the per-step vmcnt(0) barrier
// drain can't amortize; dbuf bought almost nothing (81 -> ~66us).
// Fix: W frags DIRECT from global (L2-hot 128KB, 4:1 MFMA:load ratio,
// 4x16B per wave per step) -> delete lsB + ALL per-step barriers (3 block
// barriers remain).  LDS 66.8 -> 34KB => 3-4 blocks/CU (regs ~164/wave ->
// 3 waves/SIMD) so L2 latency is TLP-hidden (unlike R17's gram-direct at
// 2:1 ratio / 2 waves/SIMD, which regressed).  gram/convW/final verbatim
// (gram 67-68us reproduced 4x).
// ---------------------------------------------------------------------------

typedef __attribute__((ext_vector_type(8))) short short8;
typedef __attribute__((ext_vector_type(4))) short short4v;
typedef __attribute__((ext_vector_type(4))) float float4v;
typedef __attribute__((ext_vector_type(8))) int int8v;
typedef __attribute__((ext_vector_type(4))) int int4v;

#if defined(__has_builtin)
#if __has_builtin(__builtin_amdgcn_exp2f)
#define EXP2F(x) __builtin_amdgcn_exp2f(x)
#endif
#endif
#ifndef EXP2F
#define EXP2F(x) __expf(0.69314718056f * (x))
#endif

__device__ __forceinline__ short f2bf(float f) {
    unsigned u = __builtin_bit_cast(unsigned, f);
    u += 0x7fffu + ((u >> 16) & 1u);          // RNE
    return (short)(u >> 16);
}

// manual fp32 -> fp8 e4m3fn (OCP), RNE.  |f| <= ~1.7 here.
__device__ __forceinline__ unsigned char f2fp8(float f) {
    float af = fabsf(f);
    unsigned s = (__builtin_bit_cast(unsigned, f) >> 31) << 7;
    if (af < 0.015625f) {                     // subnormal (<2^-6); 8 rolls up
        int q = (int)rintf(af * 512.0f);
        return (unsigned char)(s | (unsigned)q);
    }
    unsigned au = __builtin_bit_cast(unsigned, af);
    au += 0x7FFFFu + ((au >> 20) & 1u);       // RNE at bit 20
    int e = (int)(au >> 23) - 127;
    unsigned m = (au >> 20) & 7u;
    return (unsigned char)(s | (unsigned)((e + 7) << 3) | m);
}

__device__ __forceinline__ void gl_lds16(const void* g, void* l) {
    __builtin_amdgcn_global_load_lds(
        (const __attribute__((address_space(1))) void*)g,
        (__attribute__((address_space(3))) void*)l, 16, 0, 0);
}

// lsXH swizzled index (in shorts) of the 8-short group (kc 0..31, row 0..63).
// XOR of (kc&7)<<3 flips row bits 0..2 -> staging write spreads 32 lanes
// over 8 banks instead of 1.  Bijective; groups of 8 shorts stay intact.
__device__ __forceinline__ int xh_idx(int kc, int row) {
    return (((kc << 6) | row) << 3) ^ ((kc & 7) << 3);
}

// ---------------------------------------------------------------------------
// convW + zero: W1/W2 fp32 -> bf16 and zero S + out.  grid 128 x 256.
// ---------------------------------------------------------------------------
__global__ __launch_bounds__(256) void convW_zero_kernel(
    const float* __restrict__ W1, const float* __restrict__ W2,
    short* __restrict__ d1, short* __restrict__ d2,
    float* __restrict__ S, float* __restrict__ out)
{
    int i = blockIdx.x * 256 + threadIdx.x;   // 0..32767
    const float* src = (i < 16384) ? W1 : W2;
    short* dst = (i < 16384) ? d1 : d2;
    int j = i & 16383;
    float4v v = ((const float4v*)src)[j];
    short4v o;
    o.x = f2bf(v.x); o.y = f2bf(v.y); o.z = f2bf(v.z); o.w = f2bf(v.w);
    ((short4v*)dst)[j] = o;
    S[i] = 0.f;
    if (i == 0) *out = 0.f;
}

// ---------------------------------------------------------------------------
// fused proj R25: per 64-row block, 4 waves x 64 cols, NO W staging.
//   prologue: stage X tile (64x256 fp32 -> bf16) -> swizzled lsXH; barrier.
//   phase1: 8 barrier-free steps; af from lsXH, W1 frags DIRECT from
//           global (L2-hot); 16 MFMA K=32 per step.  barrier.
//   epilogue1: +b1, elu -> bf16 -> lsXH (X dead).  barrier.
//   phase2: 8 barrier-free steps with W2 direct.
//   epilogue2: +b2, rownorm -> zn8 = fp8(sqrt(2*log2e)*z/||z||).
// grid 512 x 256thr.  LDS ~34KB -> 3-4 blocks/CU (regs ~164/wave).
// ---------------------------------------------------------------------------
__global__ __launch_bounds__(256, 2) void fusedproj_kernel(
    const float* __restrict__ X1, const float* __restrict__ X2,
    const short* __restrict__ W1bf, const float* __restrict__ b1,
    const short* __restrict__ W2bf, const float* __restrict__ b2,
    unsigned char* __restrict__ zn8)
{
    __shared__ short lsXH[16384];    // 32KB X (staged,swz) then H (swz)
    __shared__ float rssq[4][64];
    __shared__ float rinv[64];

    const int arow0 = blockIdx.x * 64;
    const int tid  = threadIdx.x;
    const int w    = tid >> 6;
    const int lane = tid & 63;
    const int quad = lane >> 4;
    const int l15  = lane & 15;

    const int set = arow0 >> 14;
    const float* Xs = (set ? X2 : X1) + (size_t)(arow0 & 16383) * 256;

    // ---- prologue: X tile -> lsXH (swizzled), coalesced 1KB rows
#pragma unroll
    for (int i = 0; i < 8; ++i) {
        const int oct = i * 256 + tid;        // row = oct>>5, kc = oct&31
        const int row = oct >> 5;
        const int kc  = oct & 31;
        const float* xp = Xs + (size_t)row * 256 + kc * 8;
        float4v a0 = *(const float4v*)xp;
        float4v a1 = *(const float4v*)(xp + 4);
        short8 t;
        t[0] = f2bf(a0.x); t[1] = f2bf(a0.y);
        t[2] = f2bf(a0.z); t[3] = f2bf(a0.w);
        t[4] = f2bf(a1.x); t[5] = f2bf(a1.y);
        t[6] = f2bf(a1.z); t[7] = f2bf(a1.w);
        *(short8*)(lsXH + xh_idx(kc, row)) = t;
    }
    __syncthreads();

    float4v acc[4][4];
#pragma unroll
    for (int mi = 0; mi < 4; ++mi)
#pragma unroll
        for (int ni = 0; ni < 4; ++ni)
            acc[mi][ni] = (float4v){0.f, 0.f, 0.f, 0.f};

    // ---- phase 1: X * W1^T, 8 barrier-free steps, W1 frags from global
    for (int s = 0; s < 8; ++s) {
        const int kcg = s * 4 + quad;
        short8 af[4], bfv[4];
#pragma unroll
        for (int mi = 0; mi < 4; ++mi)
            af[mi] = *(const short8*)(lsXH + xh_idx(kcg, mi * 16 + l15));
#pragma unroll
        for (int ni = 0; ni < 4; ++ni)
            bfv[ni] = *(const short8*)(W1bf +
                (size_t)(w * 64 + ni * 16 + l15) * 256 + kcg * 8);
        __builtin_amdgcn_s_setprio(1);
#pragma unroll
        for (int mi = 0; mi < 4; ++mi)
#pragma unroll
            for (int ni = 0; ni < 4; ++ni)
                acc[mi][ni] = __builtin_amdgcn_mfma_f32_16x16x32_bf16(
                    af[mi], bfv[ni], acc[mi][ni], 0, 0, 0);
        __builtin_amdgcn_s_setprio(0);
    }
    __syncthreads();                          // all waves done reading X

    // ---- epilogue 1: +b1, elu, bf16 -> lsXH (X dead; reuse as H, swz)
    {
        const int rowbase = quad * 4;
        const int colbase = w * 64 + l15;
#pragma unroll
        for (int ni = 0; ni < 4; ++ni) {
            const int p  = colbase + ni * 16;
            const float bv = b1[p];
#pragma unroll
            for (int mi = 0; mi < 4; ++mi)
#pragma unroll
                for (int reg = 0; reg < 4; ++reg) {
                    const int row = rowbase + mi * 16 + reg;
                    float v = acc[mi][ni][reg] + bv;
                    v = (v > 0.f) ? v : expm1f(v);
                    lsXH[xh_idx(p >> 3, row) + (p & 7)] = f2bf(v);
                }
        }
    }
    __syncthreads();                          // H visible to all waves

#pragma unroll
    for (int mi = 0; mi < 4; ++mi)
#pragma unroll
        for (int ni = 0; ni < 4; ++ni)
            acc[mi][ni] = (float4v){0.f, 0.f, 0.f, 0.f};

    // ---- phase 2: H * W2^T, 8 barrier-free steps, W2 frags from global
    for (int t = 0; t < 8; ++t) {
        const int kcg = t * 4 + quad;
        short8 af[4], bfv[4];
#pragma unroll
        for (int mi = 0; mi < 4; ++mi)
            af[mi] = *(const short8*)(lsXH + xh_idx(kcg, mi * 16 + l15));
#pragma unroll
        for (int ni = 0; ni < 4; ++ni)
            bfv[ni] = *(const short8*)(W2bf +
                (size_t)(w * 64 + ni * 16 + l15) * 256 + kcg * 8);
        __builtin_amdgcn_s_setprio(1);
#pragma unroll
        for (int mi = 0; mi < 4; ++mi)
#pragma unroll
            for (int ni = 0; ni < 4; ++ni)
                acc[mi][ni] = __builtin_amdgcn_mfma_f32_16x16x32_bf16(
                    af[mi], bfv[ni], acc[mi][ni], 0, 0, 0);
        __builtin_amdgcn_s_setprio(0);
    }

    // ---- epilogue 2: +b2, normalize, fp8 out (sqrt(2*log2e) folded)
#pragma unroll
    for (int ni = 0; ni < 4; ++ni) {
        const float bv = b2[w * 64 + ni * 16 + l15];
#pragma unroll
        for (int mi = 0; mi < 4; ++mi)
#pragma unroll
            for (int reg = 0; reg < 4; ++reg)
                acc[mi][ni][reg] += bv;
    }
    float ps[4][4];
#pragma unroll
    for (int mi = 0; mi < 4; ++mi)
#pragma unroll
        for (int reg = 0; reg < 4; ++reg) {
            float s = 0.f;
#pragma unroll
            for (int ni = 0; ni < 4; ++ni) {
                float v = acc[mi][ni][reg];
                s += v * v;
            }
            s += __shfl_xor(s, 1); s += __shfl_xor(s, 2);
            s += __shfl_xor(s, 4); s += __shfl_xor(s, 8);
            ps[mi][reg] = s;
        }
    if (l15 == 0) {
#pragma unroll
        for (int mi = 0; mi < 4; ++mi)
#pragma unroll
            for (int reg = 0; reg < 4; ++reg)
                rssq[w][mi * 16 + quad * 4 + reg] = ps[mi][reg];
    }
    __syncthreads();
    if (tid < 64) {
        float ssq = rssq[0][tid] + rssq[1][tid] + rssq[2][tid] + rssq[3][tid];
        rinv[tid] = 1.69864360f / fmaxf(sqrtf(ssq), 1e-12f);
    }
    __syncthreads();

    const int bb  = (arow0 >> 12) & 3;
    const int l0  = arow0 & 4095;
    unsigned char* dst = zn8 + ((size_t)(bb * 2 + set) * 4096 + l0) * 256;
    const int colbase = w * 64 + l15;
#pragma unroll
    for (int mi = 0; mi < 4; ++mi)
#pragma unroll
        for (int reg = 0; reg < 4; ++reg) {
            const int rl = mi * 16 + quad * 4 + reg;
            const float inv = rinv[rl];
#pragma unroll
            for (int ni = 0; ni < 4; ++ni)
                dst[(size_t)rl * 256 + colbase + ni * 16] =
                    f2fp8(acc[mi][ni][reg] * inv);
        }
}

// ---------------------------------------------------------------------------
// FP8 symmetric flash-gram (R16/R21 exact, 67-68us measured 4x): grid
// 512 x 256thr (4 waves, 2wm x 2wn).  Block = (batch, pair p, quarter);
// pair = row-stripes {p, 63-p}, 65 tiles, quarters 17/16/16/16.  Dbuf
// 2x32KB B staging (gl_lds16 prefetch overlaps MFMA+epilogue); A-frags
// (fp8 regs) reloaded at the row break.  Row-sums in regs -> atomic flush
// per stripe.  Col-sums (symmetry) per off-diag tile -> non-atomic store
// into plane Cc[batch][2*row+wm][8192].  Cross tiles (tj==row+32): d-dot
// extraction.  setprio(1) wraps the MFMA cluster.  ONE barrier per tile.
// ---------------------------------------------------------------------------
#if defined(__has_builtin)
#if __has_builtin(__builtin_amdgcn_mfma_scale_f32_16x16x128_f8f6f4)
#define HAVE_MX 1
#endif
#endif

__global__ __launch_bounds__(256, 2) void gram_fp8_sym_kernel(
    const unsigned char* __restrict__ zn8, float* __restrict__ S,
    float* __restrict__ Cc, float* __restrict__ out)
{
    __shared__ unsigned char lsB[2][32768];   // [buf][kp 0..15][col 0..127][16B]

    const int bx    = blockIdx.x;             // 0..511
    const int xcd   = bx & 7;                 // batch -> XCD pair {2b,2b+1}
    const int batch = xcd >> 1;
    const int sub   = (bx >> 3) * 2 + (xcd & 1);   // 0..127
    const int p     = sub >> 2;               // pair 0..31
    const int qu    = sub & 3;                // quarter
    const int u0    = (qu == 0) ? 0 : 17 + (qu - 1) * 16;
    const int u1    = u0 + ((qu == 0) ? 17 : 16);
    const int ubrk  = 64 - p;                 // first tile index of row 63-p

    const unsigned char* Z = zn8 + (size_t)batch * 2097152;

    const int tid  = threadIdx.x;
    const int w    = tid >> 6;
    const int lane = tid & 63;
    const int wm   = w & 1;                   // 64-row band
    const int wn   = w >> 1;                  // 64-col band
    const int quad = lane >> 4;
    const int l15  = lane & 15;

#define TJ_OF(u)  ((u) < ubrk ? p + (u) : (u) - 1)
#define ROW_OF(u) ((u) < ubrk ? p : 63 - p)

#define STAGE_B(t, buf)                                                       \
    {                                                                         \
        const unsigned char* Bb = Z + (size_t)(t) * 128 * 256;                \
        _Pragma("unroll")                                                     \
        for (int r = 0; r < 8; ++r) {                                         \
            const int c   = w * 8 + r;                                        \
            const int u_  = c * 64 + lane;                                    \
            const int kp  = u_ >> 7;                                          \
            const int col = u_ & 127;                                         \
            gl_lds16(Bb + (size_t)col * 256 + kp * 16,                        \
                     &lsB[buf][(size_t)c * 1024]);                            \
        }                                                                     \
    }

    float rs[4][4];
#pragma unroll
    for (int mi = 0; mi < 4; ++mi)
#pragma unroll
        for (int reg = 0; reg < 4; ++reg)
            rs[mi][reg] = 0.f;
    float dsum = 0.f;

#define FLUSH_RS(rowstripe)                                                   \
    {                                                                         \
        float* Sr = S + (size_t)batch * 8192 + (rowstripe) * 128 + wm * 64;   \
        _Pragma("unroll")                                                     \
        for (int mi = 0; mi < 4; ++mi)                                        \
            _Pragma("unroll")                                                 \
            for (int reg = 0; reg < 4; ++reg) {                               \
                float v = rs[mi][reg];                                        \
                v += __shfl_xor(v, 1); v += __shfl_xor(v, 2);                 \
                v += __shfl_xor(v, 4); v += __shfl_xor(v, 8);                 \
                if (l15 == 0)                                                 \
                    atomicAdd(&Sr[mi * 16 + quad * 4 + reg], v);              \
                rs[mi][reg] = 0.f;                                            \
            }                                                                 \
    }

    int currow = ROW_OF(u0);

#ifdef HAVE_MX
    int8v afr[4][2];
#define LOAD_A(rowstripe)                                                     \
    {                                                                         \
        const unsigned char* Ab = Z + (size_t)((rowstripe) * 128 + wm * 64) * 256; \
        _Pragma("unroll")                                                     \
        for (int mi = 0; mi < 4; ++mi)                                        \
            _Pragma("unroll")                                                 \
            for (int ks = 0; ks < 2; ++ks) {                                  \
                const unsigned char* pA = Ab + (size_t)(mi * 16 + l15) * 256  \
                                          + ks * 128 + quad * 32;             \
                int4v lo = *(const int4v*)pA;                                 \
                int4v hi = *(const int4v*)(pA + 16);                          \
                afr[mi][ks] = __builtin_shufflevector(lo, hi, 0,1,2,3,4,5,6,7); \
            }                                                                 \
    }
#else
    long afr[4][8];
#define LOAD_A(rowstripe)                                                     \
    {                                                                         \
        const unsigned char* Ab = Z + (size_t)((rowstripe) * 128 + wm * 64) * 256; \
        _Pragma("unroll")                                                     \
        for (int mi = 0; mi < 4; ++mi)                                        \
            _Pragma("unroll")                                                 \
            for (int kc = 0; kc < 8; ++kc)                                    \
                afr[mi][kc] = *(const long*)(Ab + (size_t)(mi * 16 + l15) * 256 \
                                             + kc * 32 + quad * 8);           \
    }
#endif

    LOAD_A(currow);
    STAGE_B(TJ_OF(u0), 0);
    __syncthreads();

    for (int ui = u0; ui < u1; ++ui) {
        const int buf = (ui - u0) & 1;
        const int row = ROW_OF(ui);
        const int tj  = TJ_OF(ui);
        if (row != currow) {                  // crossed into row 63-p
            FLUSH_RS(currow);
            LOAD_A(row);
            currow = row;
        }
        if (ui + 1 < u1) STAGE_B(TJ_OF(ui + 1), buf ^ 1);

        float4v acc[4][4];
#pragma unroll
        for (int mi = 0; mi < 4; ++mi)
#pragma unroll
            for (int ni = 0; ni < 4; ++ni)
                acc[mi][ni] = (float4v){0.f, 0.f, 0.f, 0.f};

        const unsigned char* lb = &lsB[buf][0];
        __builtin_amdgcn_s_setprio(1);
#ifdef HAVE_MX
#pragma unroll
        for (int ks = 0; ks < 2; ++ks) {
            const int kp0 = ks * 8 + quad * 2;
            int8v bfv[4];
#pragma unroll
            for (int ni = 0; ni < 4; ++ni) {
                const unsigned char* pB = lb +
                    ((size_t)kp0 * 128 + wn * 64 + ni * 16 + l15) * 16;
                int4v lo = *(const int4v*)pB;
                int4v hi = *(const int4v*)(pB + 2048);   // kp0+1 slot
                bfv[ni] = __builtin_shufflevector(lo, hi, 0,1,2,3,4,5,6,7);
            }
#pragma unroll
            for (int mi = 0; mi < 4; ++mi)
#pragma unroll
                for (int ni = 0; ni < 4; ++ni)
                    acc[mi][ni] = __builtin_amdgcn_mfma_scale_f32_16x16x128_f8f6f4(
                        afr[mi][ks], bfv[ni], acc[mi][ni],
                        0, 0,                     // cbsz=E4M3, blgp=E4M3
                        0, 0x7F7F7F7F,            // scale A = 1.0
                        0, 0x7F7F7F7F);           // scale B = 1.0
        }
#else
#pragma unroll
        for (int kc = 0; kc < 8; ++kc) {
            const int kseg = kc * 4 + quad;
            const int kp   = kseg >> 1;
            const int hf   = kseg & 1;
            long bfv[4];
#pragma unroll
            for (int ni = 0; ni < 4; ++ni)
                bfv[ni] = *(const long*)(lb +
                    ((size_t)kp * 128 + wn * 64 + ni * 16 + l15) * 16 + hf * 8);
#pragma unroll
            for (int mi = 0; mi < 4; ++mi)
#pragma unroll
                for (int ni = 0; ni < 4; ++ni)
                    acc[mi][ni] = __builtin_amdgcn_mfma_f32_16x16x32_fp8_fp8(
                        afr[mi][kc], bfv[ni], acc[mi][ni], 0, 0, 0);
        }
#endif
        __builtin_amdgcn_s_setprio(0);

        // ---- cross tile: extract (q,q+4096) dots (raw acc, BEFORE exp)
        if (tj == row + 32) {
#pragma unroll
            for (int mi = 0; mi < 4; ++mi)
#pragma unroll
                for (int ni = 0; ni < 4; ++ni)
#pragma unroll
                    for (int reg = 0; reg < 4; ++reg) {
                        const int r = wm * 64 + mi * 16 + quad * 4 + reg;
                        const int c = wn * 64 + ni * 16 + l15;
                        if (r == c) dsum += acc[mi][ni][reg];
                    }
        }

        // ---- exp2 in place (acc already = 2*log2e*dot via zn8 scaling)
#pragma unroll
        for (int mi = 0; mi < 4; ++mi)
#pragma unroll
            for (int ni = 0; ni < 4; ++ni)
#pragma unroll
                for (int reg = 0; reg < 4; ++reg)
                    acc[mi][ni][reg] = EXP2F(acc[mi][ni][reg]);

        // ---- row sums accumulate in regs
#pragma unroll
        for (int mi = 0; mi < 4; ++mi)
#pragma unroll
            for (int reg = 0; reg < 4; ++reg)
                rs[mi][reg] += acc[mi][0][reg] + acc[mi][1][reg]
                             + acc[mi][2][reg] + acc[mi][3][reg];

        // ---- col sums (symmetry): per-wave 64-row partial -> own plane
        if (tj > row) {
            float* Cd = Cc + ((size_t)batch * 128 + row * 2 + wm) * 8192
                        + tj * 128 + wn * 64;
#pragma unroll
            for (int ni = 0; ni < 4; ++ni) {
                float s = 0.f;
#pragma unroll
                for (int mi = 0; mi < 4; ++mi)
#pragma unroll
                    for (int reg = 0; reg < 4; ++reg)
                        s += acc[mi][ni][reg];
                s += __shfl_xor(s, 16); s += __shfl_xor(s, 32);
                if (quad == 0)
                    Cd[ni * 16 + l15] = s;
            }
        }
        __syncthreads();                      // single per-tile barrier
    }

    FLUSH_RS(currow);

    // dv = 2*log2e * sum(d);  need -0.5*sum(d) -> factor -0.25*ln2
    {
        float dv = dsum;
        dv += __shfl_xor(dv, 1);  dv += __shfl_xor(dv, 2);
        dv += __shfl_xor(dv, 4);  dv += __shfl_xor(dv, 8);
        dv += __shfl_xor(dv, 16); dv += __shfl_xor(dv, 32);
        if (lane == 0 && dv != 0.f)
            atomicAdd(out, -0.17328680f * dv);
    }
#undef STAGE_B
#undef LOAD_A
#undef FLUSH_RS
#undef TJ_OF
#undef ROW_OF
}

// ---------------------------------------------------------------------------
// final: out += 0.125 * sum_{b,q} log(S[b][q] + sum_{r<2*(q>>7)} Cc[b][r][q] - e^2)
// grid 128 x 256 (one thread per (b,q)).  Only valid (written) planes read.
// ---------------------------------------------------------------------------
__global__ __launch_bounds__(256) void final_log_kernel(
    const float* __restrict__ S, const float* __restrict__ Cc,
    float* __restrict__ out)
{
    __shared__ float red[4];
    const int tid  = threadIdx.x;
    const int w    = tid >> 6;
    const int lane = tid & 63;
    const float E2 = 7.3890560989306495f;

    const int i = blockIdx.x * 256 + tid;     // 0..32767
    const int b = i >> 13;
    const int q = i & 8191;
    float s = S[i];
    const float* Cp = Cc + (size_t)b * 128 * 8192 + q;
    const int np = (q >> 7) * 2;              // planes 0..np-1 are written
    for (int r = 0; r < np; ++r)
        s += Cp[(size_t)r * 8192];
    float acc = logf(s - E2);

    acc += __shfl_xor(acc, 1);  acc += __shfl_xor(acc, 2);
    acc += __shfl_xor(acc, 4);  acc += __shfl_xor(acc, 8);
    acc += __shfl_xor(acc, 16); acc += __shfl_xor(acc, 32);
    if (lane == 0) red[w] = acc;
    __syncthreads();
    if (tid == 0)
        atomicAdd(out, 0.125f * (red[0] + red[1] + red[2] + red[3]));
}

// ---------------------------------------------------------------------------
// Workspace (bytes), total ~25.6 MB:
//   [0,       131072)  S (4*8192 fp32)
//   [131072,  262144)  W1bf
//   [262144,  393216)  W2bf
//   [393216,  8781824) zn8 (fp8, 8.39MB)
//   [8781824, 25559040) Cc (col-sum planes, 4*128*8192 fp32 = 16.78MB;
//                      no memset: final reads only written planes)
// ---------------------------------------------------------------------------
extern "C" void kernel_launch(void* const* d_in, const int* in_sizes, int n_in,
                              void* d_out, int out_size, void* d_ws, size_t ws_size,
                              hipStream_t stream)
{
    const float* X1 = (const float*)d_in[0];
    const float* X2 = (const float*)d_in[1];
    const float* W1 = (const float*)d_in[2];
    const float* b1 = (const float*)d_in[3];
    const float* W2 = (const float*)d_in[4];
    const float* b2 = (const float*)d_in[5];

    char* ws = (char*)d_ws;
    float* S    = (float*)(ws + 0);
    short* W1bf = (short*)(ws + 131072);
    short* W2bf = (short*)(ws + 262144);
    unsigned char* zn8 = (unsigned char*)(ws + 393216);
    float* Cc   = (float*)(ws + 8781824);

    convW_zero_kernel<<<128, 256, 0, stream>>>(W1, W2, W1bf, W2bf,
                                               S, (float*)d_out);
    fusedproj_kernel<<<512, 256, 0, stream>>>(X1, X2, W1bf, b1, W2bf, b2, zn8);
    gram_fp8_sym_kernel<<<512, 256, 0, stream>>>(zn8, S, Cc, (float*)d_out);
    final_log_kernel<<<128, 256, 0, stream>>>(S, Cc, (float*)d_out);
}